// Round 9
// baseline (322.269 us; speedup 1.0000x reference)
//
#include <hip/hip_runtime.h>
#include <math.h>

// ---------------- problem constants ----------------
#define NB 32      // molecules
#define NA 24      // atoms
#define EMBED 32
#define C_FEAT 128 // 24 + 12*3 + 8*5 + 4*7
#define C_OUT 152  // 48 + 12*3 + 8*5 + 4*7

// ---------------- constexpr path table ----------------
struct PathC { int li, mi, lo, mo, lf, woff, toff, ci0, obase, pobase; float scale; };
struct PTable { PathC p[72]; };

constexpr double csqrt_(double x){ double g = x < 1.0 ? 1.0 : x; for(int i=0;i<48;++i) g = 0.5*(g + x/g); return g; }

constexpr PTable build_paths(){
  PTable t{};
  int off=0, n=0;
  for(int layer=0; layer<3; ++layer){
    int toff=0, pobase=0;
    const int nin = (layer==0)?1:4;
    for(int ii=0; ii<nin; ++ii){
      const int mi_a[4]={24,12,8,4};
      const int ci0_a[4]={0,24,60,100};
      const int mi = (layer==0)?32:mi_a[ii];
      const int li = (layer==0)?0:ii;
      const int ci0 = (layer==0)?0:ci0_a[ii];
      const int mo_a[4]={48,12,8,4};
      const int ob_a[4]={0,48,84,124};
      for(int oo=0; oo<4; ++oo){
        int mo=mo_a[oo], lo=oo;
        int lfmin = li>lo? li-lo : lo-li;
        int lfmax = (li+lo)<3 ? (li+lo) : 3;
        for(int lf=lfmin; lf<=lfmax; ++lf){
          int dlo=2*lo+1;
          t.p[n].li=li; t.p[n].mi=mi; t.p[n].lo=lo; t.p[n].mo=mo; t.p[n].lf=lf;
          t.p[n].woff=off; t.p[n].toff=toff; t.p[n].ci0=ci0; t.p[n].obase=ob_a[lo];
          t.p[n].pobase=pobase;
          t.p[n].scale=(float)(1.0/(csqrt_(10.0*mi)*csqrt_(18.0)));
          off += 10*mo*mi;
          toff += mi*dlo;
          pobase += dlo;
          ++n;
        }
      }
    }
  }
  return t;
}
constexpr int total_woff(){
  PTable t = build_paths();
  return t.p[71].woff + 10*t.p[71].mo*t.p[71].mi;
}
static_assert(total_woff()==114880, "weight offset mismatch");
__constant__ PTable c_paths = build_paths();

// ---------------- constexpr real Clebsch-Gordan ----------------
constexpr double cfact_(int n){ double r=1.0; for(int i=2;i<=n;++i) r*=(double)i; return r; }

constexpr double ccg_(int j1,int m1,int j2,int m2,int j3,int m3){
  if (m1+m2 != m3) return 0.0;
  double pre = csqrt_((2.0*j3+1.0) * cfact_(j3+j1-j2)*cfact_(j3-j1+j2)*cfact_(j1+j2-j3)/cfact_(j1+j2+j3+1));
  pre *= csqrt_(cfact_(j3+m3)*cfact_(j3-m3)*cfact_(j1-m1)*cfact_(j1+m1)*cfact_(j2-m2)*cfact_(j2+m2));
  double s=0.0;
  for(int k=0;k<=j1+j2+j3;++k){
    int a1=k, a2=j1+j2-j3-k, a3=j1-m1-k, a4=j2+m2-k, a5=j3-j2+m1+k, a6=j3-j1-m2+k;
    if(a1<0||a2<0||a3<0||a4<0||a5<0||a6<0) continue;
    double d = cfact_(a1)*cfact_(a2)*cfact_(a3)*cfact_(a4)*cfact_(a5)*cfact_(a6);
    s += ((k&1)? -1.0:1.0)/d;
  }
  return pre*s;
}

struct C2d { double r, i; };
// U[a][ic] for Y^R = U @ Y^C; each row has <=2 nonzeros at ic in {a, 2l-a}
constexpr C2d uent_(int l, int a, int ic){
  const double s = 0.70710678118654752440;
  int m = a - l;
  if(m==0) return (ic==l)? C2d{1.0,0.0} : C2d{0.0,0.0};
  if(m>0){
    if(ic==a)     return C2d{ (m&1)? -s : s, 0.0};
    if(ic==2*l-a) return C2d{ s, 0.0};
    return C2d{0.0,0.0};
  }
  int aa = -m;
  if(ic==a)     return C2d{0.0, s};
  if(ic==2*l-a) return C2d{0.0, (aa&1)? s : -s};
  return C2d{0.0,0.0};
}

struct CGT { float v[343]; };

template<int L1,int L2,int L3>
constexpr CGT make_cg_(){
  constexpr int d1=2*L1+1, d2=2*L2+1, d3=2*L3+1;
  double cgv[d1*d2] = {};
  for(int i=0;i<d1;++i) for(int j=0;j<d2;++j){
    int m1=i-L1, m2=j-L2, m3=m1+m2;
    cgv[i*d2+j] = (m3>=-L3 && m3<=L3) ? ccg_(L1,m1,L2,m2,L3,m3) : 0.0;
  }
  double Tr[d1*d2*d3]={}, Ti[d1*d2*d3]={};
  double sr=0.0, si=0.0;
  for(int a=0;a<d1;++a) for(int bb=0;bb<d2;++bb) for(int c=0;c<d3;++c){
    double tr=0.0, ti=0.0;
    for(int s1=0;s1<2;++s1){
      int ic = s1? 2*L1-a : a;
      if(s1 && ic==a) continue;
      C2d A = uent_(L1,a,ic);
      if(A.r==0.0 && A.i==0.0) continue;
      for(int s2=0;s2<2;++s2){
        int jc = s2? 2*L2-bb : bb;
        if(s2 && jc==bb) continue;
        C2d Bc = uent_(L2,bb,jc);
        if(Bc.r==0.0 && Bc.i==0.0) continue;
        int m1=ic-L1, m2=jc-L2, m3=m1+m2;
        if(m3<-L3||m3>L3) continue;
        C2d Cc = uent_(L3,c,m3+L3);   // take conj below
        if(Cc.r==0.0 && Cc.i==0.0) continue;
        double cg = cgv[ic*d2+jc];
        double abr = A.r*Bc.r - A.i*Bc.i;
        double abi = A.r*Bc.i + A.i*Bc.r;
        tr += (abr*Cc.r + abi*Cc.i)*cg;   // Re(ab * conj(C))
        ti += (abi*Cc.r - abr*Cc.i)*cg;   // Im(ab * conj(C))
      }
    }
    int e=(a*d2+bb)*d3+c;
    Tr[e]=tr; Ti[e]=ti;
    sr += (tr<0.0? -tr:tr); si += (ti<0.0? -ti:ti);
  }
  CGT o{};
  bool re = (sr>=si);
  for(int e=0;e<d1*d2*d3;++e) o.v[e] = (float)(re? Tr[e] : Ti[e]);
  return o;
}

template<int A,int B,int C> struct CGH { static constexpr CGT t = make_cg_<A,B,C>(); };

constexpr CGT get_cg_(int l1,int l2,int l3){
  if(l1==0){
    if(l2==0) return CGH<0,0,0>::t;
    if(l2==1) return CGH<0,1,1>::t;
    if(l2==2) return CGH<0,2,2>::t;
    return CGH<0,3,3>::t;
  }
  if(l1==1){
    if(l3==0) return CGH<1,1,0>::t;
    if(l3==1){ if(l2==0) return CGH<1,0,1>::t; if(l2==1) return CGH<1,1,1>::t; return CGH<1,2,1>::t; }
    if(l3==2){ if(l2==1) return CGH<1,1,2>::t; if(l2==2) return CGH<1,2,2>::t; return CGH<1,3,2>::t; }
    { if(l2==2) return CGH<1,2,3>::t; return CGH<1,3,3>::t; }
  }
  if(l1==2){
    if(l3==0) return CGH<2,2,0>::t;
    if(l3==1){ if(l2==1) return CGH<2,1,1>::t; if(l2==2) return CGH<2,2,1>::t; return CGH<2,3,1>::t; }
    if(l3==2){ if(l2==0) return CGH<2,0,2>::t; if(l2==1) return CGH<2,1,2>::t; if(l2==2) return CGH<2,2,2>::t; return CGH<2,3,2>::t; }
    { if(l2==1) return CGH<2,1,3>::t; if(l2==2) return CGH<2,2,3>::t; return CGH<2,3,3>::t; }
  }
  {
    if(l3==0) return CGH<3,3,0>::t;
    if(l3==1){ if(l2==2) return CGH<3,2,1>::t; return CGH<3,3,1>::t; }
    if(l3==2){ if(l2==1) return CGH<3,1,2>::t; if(l2==2) return CGH<3,2,2>::t; return CGH<3,3,2>::t; }
    { if(l2==0) return CGH<3,0,3>::t; if(l2==1) return CGH<3,1,3>::t; if(l2==2) return CGH<3,2,3>::t; return CGH<3,3,3>::t; }
  }
}

// ---------------- constexpr bucketed sparse tables ----------------
struct F2 { float x, y; };   // (coef, (float)A-index)
// t-item u32: waddr(11) | base(7)<<11 | listEntryBase<<18
// u-item u16: prel<<6 | u        (stage-out, sorted by mi*dlo desc)
template<int NTC,int NCC,int NUC>
struct BT {
  unsigned titem[NTC];
  F2 cpk[NCC];
  unsigned short uitem[NUC];
  int nt4, nt48, nt, nc, nu, ok;
};

template<int PB,int PE,int CIN,int NTC,int NCC,int NUC>
constexpr BT<NTC,NCC,NUC> build_class_(){
  BT<NTC,NCC,NUC> bt{};
  PTable pt = build_paths();
  int lb_[160]={}; int pl_[160]={};
  int nc=0, ok=1;
  for(int p=PB;p<PE;++p){
    PathC pc = pt.p[p];
    int dli=2*pc.li+1, dlf=2*pc.lf+1, dlo=2*pc.lo+1, foff=pc.lf*pc.lf;
    CGT t = get_cg_(pc.li,pc.lf,pc.lo);
    for(int o=0;o<dlo;++o){
      int lidx = pc.pobase + o;
      int start = nc;
      for(int i=0;i<dli;++i) for(int f=0;f<dlf;++f){
        double val = (double)t.v[(i*dlf+f)*dlo+o];
        if(val>1e-12 || val<-1e-12){
          if(nc<NCC){ bt.cpk[nc].x=(float)val; bt.cpk[nc].y=(float)((foff+f)*CIN+i); }
          else ok=0;
          ++nc;
        }
      }
      int len = nc-start;
      int plen = len<=4?4 : (len<=8?8:16);
      if(len>16) ok=0;
      for(int nn=len;nn<plen;++nn){ if(nc<NCC){ bt.cpk[nc].x=0.f; bt.cpk[nc].y=0.f; } else ok=0; ++nc; }
      lb_[lidx]=start; pl_[lidx]=plen;
    }
  }
  bt.nc=nc; if(nc>NCC) ok=0;
  int nt=0;
  for(int pass=0;pass<3;++pass){
    int want = pass==0?4 : (pass==1?8:16);
    for(int p=PB;p<PE;++p){
      PathC pc = pt.p[p];
      int dli=2*pc.li+1, dlo=2*pc.lo+1;
      for(int o=0;o<dlo;++o){
        int lidx = pc.pobase + o;
        if(pl_[lidx]!=want) continue;
        for(int v=0;v<pc.mi;++v){
          unsigned waddr=(unsigned)(pc.toff + o*pc.mi + v);
          unsigned base =(unsigned)(pc.ci0 + v*dli);
          if(nt<NTC) bt.titem[nt] = waddr | (base<<11) | ((unsigned)lb_[lidx]<<18);
          ++nt;
        }
      }
    }
    if(pass==0) bt.nt4=nt;
    if(pass==1) bt.nt48=nt;
  }
  bt.nt=nt; if(nt!=NTC) ok=0;

  // ---- u-items: one per (path, u), sorted by cost = mi*dlo descending ----
  unsigned short tmp[NUC]={}; int tcost[NUC]={};
  int nu=0;
  for(int p=PB;p<PE;++p){
    PathC pc = pt.p[p]; int dlo=2*pc.lo+1;
    for(int u=0;u<pc.mo;++u){
      if(nu<NUC){ tmp[nu]=(unsigned short)(((p-PB)<<6)|u); tcost[nu]=pc.mi*dlo; }
      ++nu;
    }
  }
  if(nu!=NUC) ok=0;
  // distinct cost values, sorted desc
  int cvs[24]={}; int ncv=0;
  for(int i=0;i<NUC;++i){
    int c=tcost[i]; bool f=false;
    for(int j=0;j<ncv;++j) if(cvs[j]==c) f=true;
    if(!f && ncv<24) cvs[ncv++]=c;
  }
  for(int i=0;i<ncv;++i){ int bi=i;
    for(int j=i+1;j<ncv;++j) if(cvs[j]>cvs[bi]) bi=j;
    int t2=cvs[i]; cvs[i]=cvs[bi]; cvs[bi]=t2;
  }
  int m=0;
  for(int ci=0;ci<ncv;++ci)
    for(int i=0;i<NUC;++i) if(tcost[i]==cvs[ci]) bt.uitem[m++]=tmp[i];
  if(m!=NUC) ok=0;
  bt.nu=nu;
  bt.ok=ok;
  return bt;
}

constexpr auto BL0v  = build_class_<0,4,32,  512, 128, 72>();
constexpr auto BL12v = build_class_<4,38,128,1460,2560,428>();
static_assert(BL0v.ok==1,  "L0 table overflow");
static_assert(BL12v.ok==1, "L12 table overflow");
static_assert(BL0v.nt4==512, "L0 all len<=4");
__constant__ BT<512,128,72>     c_BL0  = BL0v;
__constant__ BT<1460,2560,428>  c_BL12 = BL12v;

// ---------------- stage T bucket helper ----------------
template<int PL>
__device__ __forceinline__ void bucketT_(const unsigned* __restrict__ ti,
                                         const F2* __restrict__ cpk,
                                         const float* sA, float* sT,
                                         int i0, int i1, int tid){
  for(int i=i0+tid; i<i1; i+=256){
    unsigned e = ti[i];
    int waddr = e & 2047;
    int base  = (e>>11)&127;
    int lb    = (int)(e>>18);
    float s0 = 0.f, s1 = 0.f;   // two partial chains halve FMA dependency depth
    #pragma unroll
    for(int n=0;n<PL;n+=2){
      F2 c0 = cpk[lb+n], c1 = cpk[lb+n+1];
      s0 += c0.x * sA[(int)c0.y + base];
      s1 += c1.x * sA[(int)c1.y + base];
    }
    sT[waddr] = s0 + s1;
  }
}

// ---------------- stage-out u-item helper: W row read ONCE, all dlo outputs ----------------
template<int DLO>
__device__ __forceinline__ void uitem_(const float4* __restrict__ Wp, const float4* __restrict__ T4,
                                       float* s_out, int mi4, int t4b, int ob, float scale){
  float acc[DLO];
  #pragma unroll
  for(int o=0;o<DLO;++o) acc[o]=0.f;
  for(int v4=0; v4<mi4; ++v4){
    float4 w = Wp[v4];
    #pragma unroll
    for(int o=0;o<DLO;++o){
      float4 t = T4[t4b + o*mi4 + v4];
      acc[o] += w.x*t.x + w.y*t.y + w.z*t.z + w.w*t.w;
    }
  }
  #pragma unroll
  for(int o=0;o<DLO;++o) atomicAdd(&s_out[ob+o], acc[o]*scale);
}

// ---------------- per-layer kernel: one radial basis k per block ----------------
template<int L>
__global__ __launch_bounds__(256,5) void layer_kernel(
    const float* __restrict__ fin, const int* __restrict__ z, const float* __restrict__ table,
    const float* __restrict__ pos, const float* __restrict__ maskp,
    const float* __restrict__ rw, float* __restrict__ pout)
{
  constexpr int C_IN = (L==0)?32:128;
  constexpr int PBEG = (L==0)?0:(L==1?4:38);
  constexpr int NT   = (L==0)?512:1460;
  constexpr int NU   = (L==0)?72:428;
  constexpr int NT4  = (L==0)?BL0v.nt4 :BL12v.nt4;
  constexpr int NT48 = (L==0)?BL0v.nt48:BL12v.nt48;
  constexpr int NI_U = (NU+255)/256;

  __shared__ __align__(16) float s_fin[NA*C_IN];
  __shared__ __align__(16) float s_A[16*C_IN];
  __shared__ __align__(16) float s_T[NT];
  __shared__ float s_Y[NA*16];
  __shared__ float s_rb[NA];
  __shared__ float s_out[C_OUT];

  const int tid = threadIdx.x;
  const int b = blockIdx.x / NA, a = blockIdx.x % NA;
  const int k = blockIdx.y;

  const unsigned* TI; const F2* CP; const unsigned short* UT;
  if constexpr(L==0){ TI=c_BL0.titem;  CP=c_BL0.cpk;  UT=c_BL0.uitem; }
  else              { TI=c_BL12.titem; CP=c_BL12.cpk; UT=c_BL12.uitem; }

  // ---- prologue ----
  if(tid < C_OUT) s_out[tid] = 0.f;

  if(tid < NA){    // Y[16] + rb (this block's k) per neighbour j
    const int j = tid;
    const float* pa = pos + (b*NA+a)*3;
    const float* pj = pos + (b*NA+j)*3;
    float dx=pj[0]-pa[0], dy=pj[1]-pa[1], dz=pj[2]-pa[2];
    float r = sqrtf(dx*dx+dy*dy+dz*dz + 1e-12f);
    float inv = 1.f/(r + 1e-9f);
    float x=dx*inv, y=dy*inv, zz=dz*inv;
    float r2 = x*x+y*y+zz*zz;
    float* Yp = s_Y + j*16;
    Yp[0] = 0.28209479177387814f;
    Yp[1] = 0.4886025119029199f*y;
    Yp[2] = 0.4886025119029199f*zz;
    Yp[3] = 0.4886025119029199f*x;
    Yp[4] = 1.0925484305920792f*x*y;
    Yp[5] = 1.0925484305920792f*y*zz;
    Yp[6] = 0.31539156525252005f*(3.f*zz*zz - r2);
    Yp[7] = 1.0925484305920792f*x*zz;
    Yp[8] = 0.5462742152960396f*(x*x - y*y);
    Yp[9] = 0.5900435899266435f*y*(3.f*x*x - y*y);
    Yp[10]= 2.890611442640554f*x*y*zz;
    Yp[11]= 0.4570457994644658f*y*(5.f*zz*zz - r2);
    Yp[12]= 0.3731763325901154f*zz*(5.f*zz*zz - 3.f*r2);
    Yp[13]= 0.4570457994644658f*x*(5.f*zz*zz - r2);
    Yp[14]= 1.445305721320277f*zz*(x*x - y*y);
    Yp[15]= 0.5900435899266435f*x*(x*x - 3.f*y*y);
    float ck = (5.f/9.f)*(float)k;
    float tt = (r-ck)*(9.f/5.f);
    s_rb[j] = expf(-0.5f*tt*tt)*maskp[b*NA+j];
  }

  if(L==0){
    for(int i=tid;i<NA*EMBED;i+=256){
      int j = i>>5, c = i&31;
      s_fin[i] = table[z[b*NA+j]*EMBED + c];
    }
  } else {
    const float4* fg = reinterpret_cast<const float4*>(fin + b*NA*C_IN);
    float4* fs = reinterpret_cast<float4*>(s_fin);
    #pragma unroll
    for(int r=0;r<(NA*C_IN/4+255)/256;++r){
      int i = tid + r*256;
      if(i < NA*C_IN/4) fs[i] = fg[i];
    }
  }
  __syncthreads();

  // ---- stage A: A[f][c] = sum_j rb[j]*Y[j,f]*fin[j,c] ----
  {
    const float4* fs4 = reinterpret_cast<const float4*>(s_fin);
    float4* sA4 = reinterpret_cast<float4*>(s_A);
    if(L==0){
      if(tid < 128){
        int f = tid>>3, c4 = tid&7;
        float4 s0 = {0.f,0.f,0.f,0.f};
        #pragma unroll
        for(int j=0;j<NA;++j){
          float ry = s_rb[j]*s_Y[j*16+f];
          float4 v = fs4[j*8 + c4];
          s0.x += ry*v.x; s0.y += ry*v.y; s0.z += ry*v.z; s0.w += ry*v.w;
        }
        sA4[f*8 + c4] = s0;
      }
    } else {
      int f0 = tid>>5, c4 = tid&31;     // rows f0 and f0+8
      float4 a0={0,0,0,0}, a1={0,0,0,0};
      #pragma unroll
      for(int j=0;j<NA;++j){
        float rbv = s_rb[j];
        float y0 = rbv*s_Y[j*16+f0];
        float y1 = rbv*s_Y[j*16+f0+8];
        float4 v = fs4[j*32 + c4];
        a0.x += y0*v.x; a0.y += y0*v.y; a0.z += y0*v.z; a0.w += y0*v.w;
        a1.x += y1*v.x; a1.y += y1*v.y; a1.z += y1*v.z; a1.w += y1*v.w;
      }
      sA4[(f0  )*32 + c4] = a0;
      sA4[(f0+8)*32 + c4] = a1;
    }
  }
  __syncthreads();

  // ---- stage T: sparse CG contraction ----
  bucketT_<4 >(TI, CP, s_A, s_T, 0,    NT4,  tid);
  bucketT_<8 >(TI, CP, s_A, s_T, NT4,  NT48, tid);
  bucketT_<16>(TI, CP, s_A, s_T, NT48, NT,   tid);
  __syncthreads();

  // ---- stage out (u-major): W row read once, all dlo outputs computed ----
  const float4* T4 = reinterpret_cast<const float4*>(s_T);
  #pragma unroll
  for(int r=0;r<NI_U;++r){
    int idx = tid + r*256;
    if(idx < NU){
      unsigned e = UT[idx];
      int prel=e>>6, u=e&63;
      const PathC pc = c_paths.p[prel+PBEG];
      const int dlo = 2*pc.lo+1;
      const float4* Wp = reinterpret_cast<const float4*>(rw + pc.woff + (u + k*pc.mo)*pc.mi);
      const int mi4 = pc.mi>>2;
      const int t4b = pc.toff>>2;
      const int ob  = pc.obase + u*dlo;
      switch(dlo){
        case 1: uitem_<1>(Wp, T4, s_out, mi4, t4b, ob, pc.scale); break;
        case 3: uitem_<3>(Wp, T4, s_out, mi4, t4b, ob, pc.scale); break;
        case 5: uitem_<5>(Wp, T4, s_out, mi4, t4b, ob, pc.scale); break;
        default: uitem_<7>(Wp, T4, s_out, mi4, t4b, ob, pc.scale); break;
      }
    }
  }
  __syncthreads();

  // ---- write this k's partial ----
  if(tid < C_OUT)
    pout[(k*NB*NA + blockIdx.x)*C_OUT + tid] = s_out[tid];
}

// ---------------- epilogue: sum k-partials, gate, mask ----------------
__global__ __launch_bounds__(160) void epi_kernel(const float* __restrict__ part,
    const float* __restrict__ maskp, float* __restrict__ fout){
  __shared__ float so[C_OUT];
  __shared__ float sg[24];
  const int ba = blockIdx.x, t = threadIdx.x;
  if(t < C_OUT){
    float s = 0.f;
    #pragma unroll
    for(int kk=0;kk<10;++kk) s += part[(kk*NB*NA + ba)*C_OUT + t];
    so[t] = s;
  }
  __syncthreads();
  if(t < 24) sg[t] = 1.f/(1.f+expf(-so[24+t]));
  __syncthreads();
  if(t < C_FEAT){
    float val;
    if(t<24)       { val = fmaxf(so[t], 0.f); }
    else if(t<60)  { int r=t-24;  int v=r/3; val = so[48+r]  * sg[v]; }
    else if(t<100) { int r=t-60;  int v=r/5; val = so[84+r]  * sg[12+v]; }
    else           { int r=t-100; int v=r/7; val = so[124+r] * sg[20+v]; }
    fout[ba*C_FEAT + t] = val*maskp[ba];
  }
}

// ---------------- launch ----------------
extern "C" void kernel_launch(void* const* d_in, const int* in_sizes, int n_in,
                              void* d_out, int out_size, void* d_ws, size_t ws_size,
                              hipStream_t stream) {
  const int*   z     = (const int*)  d_in[0];
  const float* pos   = (const float*)d_in[1];
  const float* mask  = (const float*)d_in[2];
  const float* table = (const float*)d_in[3];
  const float* rw    = (const float*)d_in[4];
  float* out = (float*)d_out;
  float* ws  = (float*)d_ws;

  float* ps = ws;                        // 10*768*152 = 1,167,360 floats
  float* fA = ps + 10*NB*NA*C_OUT;       // 768*128
  float* fB = fA + NB*NA*C_FEAT;

  dim3 gl(NB*NA, 10);
  layer_kernel<0><<<gl, 256, 0, stream>>>(nullptr, z, table, pos, mask, rw, ps);
  epi_kernel<<<NB*NA, 160, 0, stream>>>(ps, mask, fA);
  layer_kernel<1><<<gl, 256, 0, stream>>>(fA, z, table, pos, mask, rw, ps);
  epi_kernel<<<NB*NA, 160, 0, stream>>>(ps, mask, fB);
  layer_kernel<2><<<gl, 256, 0, stream>>>(fB, z, table, pos, mask, rw, ps);
  epi_kernel<<<NB*NA, 160, 0, stream>>>(ps, mask, out);
}

// Round 12
// 266.980 us; speedup vs baseline: 1.2071x; 1.2071x over previous
//
#include <hip/hip_runtime.h>
#include <math.h>

// ---------------- problem constants ----------------
#define NB 32      // molecules
#define NA 24      // atoms
#define EMBED 32
#define C_FEAT 128 // 24 + 12*3 + 8*5 + 4*7
#define C_OUT 152  // 48 + 12*3 + 8*5 + 4*7

// ---------------- constexpr path table (host-side only) ----------------
struct PathC { int li, mi, lo, mo, lf, woff, toff, ci0, obase, pobase; float scale; };
struct PTable { PathC p[72]; };

constexpr double csqrt_(double x){ double g = x < 1.0 ? 1.0 : x; for(int i=0;i<48;++i) g = 0.5*(g + x/g); return g; }

constexpr PTable build_paths(){
  PTable t{};
  int off=0, n=0;
  for(int layer=0; layer<3; ++layer){
    int toff=0, pobase=0;
    const int nin = (layer==0)?1:4;
    for(int ii=0; ii<nin; ++ii){
      const int mi_a[4]={24,12,8,4};
      const int ci0_a[4]={0,24,60,100};
      const int mi = (layer==0)?32:mi_a[ii];
      const int li = (layer==0)?0:ii;
      const int ci0 = (layer==0)?0:ci0_a[ii];
      const int mo_a[4]={48,12,8,4};
      const int ob_a[4]={0,48,84,124};
      for(int oo=0; oo<4; ++oo){
        int mo=mo_a[oo], lo=oo;
        int lfmin = li>lo? li-lo : lo-li;
        int lfmax = (li+lo)<3 ? (li+lo) : 3;
        for(int lf=lfmin; lf<=lfmax; ++lf){
          int dlo=2*lo+1;
          t.p[n].li=li; t.p[n].mi=mi; t.p[n].lo=lo; t.p[n].mo=mo; t.p[n].lf=lf;
          t.p[n].woff=off; t.p[n].toff=toff; t.p[n].ci0=ci0; t.p[n].obase=ob_a[lo];
          t.p[n].pobase=pobase;
          t.p[n].scale=(float)(1.0/(csqrt_(10.0*mi)*csqrt_(18.0)));
          off += 10*mo*mi;
          toff += mi*dlo;
          pobase += dlo;
          ++n;
        }
      }
    }
  }
  return t;
}
constexpr int total_woff(){
  PTable t = build_paths();
  return t.p[71].woff + 10*t.p[71].mo*t.p[71].mi;
}
static_assert(total_woff()==114880, "weight offset mismatch");

// Layer-2 reuses the layer-1 item tables; its weights start W_DELTA floats later.
constexpr int w_delta_(){ PTable t = build_paths(); return t.p[38].woff - t.p[4].woff; }
constexpr int W_DELTA4 = w_delta_()/4;
// verify the layer1->layer2 weight-offset shift is uniform across all 34 paths
constexpr bool wshift_uniform_(){
  PTable t = build_paths();
  for(int i=0;i<34;++i) if(t.p[38+i].woff - t.p[4+i].woff != w_delta_()) return false;
  for(int i=0;i<34;++i) if(t.p[38+i].mi != t.p[4+i].mi || t.p[38+i].mo != t.p[4+i].mo
                        || t.p[38+i].toff != t.p[4+i].toff) return false;
  return true;
}
static_assert(wshift_uniform_(), "layer1/layer2 weight shift not uniform");
static_assert((w_delta_() & 3) == 0, "W_DELTA not float4 aligned");

// ---------------- constexpr real Clebsch-Gordan ----------------
constexpr double cfact_(int n){ double r=1.0; for(int i=2;i<=n;++i) r*=(double)i; return r; }

constexpr double ccg_(int j1,int m1,int j2,int m2,int j3,int m3){
  if (m1+m2 != m3) return 0.0;
  double pre = csqrt_((2.0*j3+1.0) * cfact_(j3+j1-j2)*cfact_(j3-j1+j2)*cfact_(j1+j2-j3)/cfact_(j1+j2+j3+1));
  pre *= csqrt_(cfact_(j3+m3)*cfact_(j3-m3)*cfact_(j1-m1)*cfact_(j1+m1)*cfact_(j2-m2)*cfact_(j2+m2));
  double s=0.0;
  for(int k=0;k<=j1+j2+j3;++k){
    int a1=k, a2=j1+j2-j3-k, a3=j1-m1-k, a4=j2+m2-k, a5=j3-j2+m1+k, a6=j3-j1-m2+k;
    if(a1<0||a2<0||a3<0||a4<0||a5<0||a6<0) continue;
    double d = cfact_(a1)*cfact_(a2)*cfact_(a3)*cfact_(a4)*cfact_(a5)*cfact_(a6);
    s += ((k&1)? -1.0:1.0)/d;
  }
  return pre*s;
}

struct C2d { double r, i; };
// U[a][ic] for Y^R = U @ Y^C; each row has <=2 nonzeros at ic in {a, 2l-a}
constexpr C2d uent_(int l, int a, int ic){
  const double s = 0.70710678118654752440;
  int m = a - l;
  if(m==0) return (ic==l)? C2d{1.0,0.0} : C2d{0.0,0.0};
  if(m>0){
    if(ic==a)     return C2d{ (m&1)? -s : s, 0.0};
    if(ic==2*l-a) return C2d{ s, 0.0};
    return C2d{0.0,0.0};
  }
  int aa = -m;
  if(ic==a)     return C2d{0.0, s};
  if(ic==2*l-a) return C2d{0.0, (aa&1)? s : -s};
  return C2d{0.0,0.0};
}

struct CGT { float v[343]; };

template<int L1,int L2,int L3>
constexpr CGT make_cg_(){
  constexpr int d1=2*L1+1, d2=2*L2+1, d3=2*L3+1;
  double cgv[d1*d2] = {};
  for(int i=0;i<d1;++i) for(int j=0;j<d2;++j){
    int m1=i-L1, m2=j-L2, m3=m1+m2;
    cgv[i*d2+j] = (m3>=-L3 && m3<=L3) ? ccg_(L1,m1,L2,m2,L3,m3) : 0.0;
  }
  double Tr[d1*d2*d3]={}, Ti[d1*d2*d3]={};
  double sr=0.0, si=0.0;
  for(int a=0;a<d1;++a) for(int bb=0;bb<d2;++bb) for(int c=0;c<d3;++c){
    double tr=0.0, ti=0.0;
    for(int s1=0;s1<2;++s1){
      int ic = s1? 2*L1-a : a;
      if(s1 && ic==a) continue;
      C2d A = uent_(L1,a,ic);
      if(A.r==0.0 && A.i==0.0) continue;
      for(int s2=0;s2<2;++s2){
        int jc = s2? 2*L2-bb : bb;
        if(s2 && jc==bb) continue;
        C2d Bc = uent_(L2,bb,jc);
        if(Bc.r==0.0 && Bc.i==0.0) continue;
        int m1=ic-L1, m2=jc-L2, m3=m1+m2;
        if(m3<-L3||m3>L3) continue;
        C2d Cc = uent_(L3,c,m3+L3);   // take conj below
        if(Cc.r==0.0 && Cc.i==0.0) continue;
        double cg = cgv[ic*d2+jc];
        double abr = A.r*Bc.r - A.i*Bc.i;
        double abi = A.r*Bc.i + A.i*Bc.r;
        tr += (abr*Cc.r + abi*Cc.i)*cg;   // Re(ab * conj(C))
        ti += (abi*Cc.r - abr*Cc.i)*cg;   // Im(ab * conj(C))
      }
    }
    int e=(a*d2+bb)*d3+c;
    Tr[e]=tr; Ti[e]=ti;
    sr += (tr<0.0? -tr:tr); si += (ti<0.0? -ti:ti);
  }
  CGT o{};
  bool re = (sr>=si);
  for(int e=0;e<d1*d2*d3;++e) o.v[e] = (float)(re? Tr[e] : Ti[e]);
  return o;
}

template<int A,int B,int C> struct CGH { static constexpr CGT t = make_cg_<A,B,C>(); };

constexpr CGT get_cg_(int l1,int l2,int l3){
  if(l1==0){
    if(l2==0) return CGH<0,0,0>::t;
    if(l2==1) return CGH<0,1,1>::t;
    if(l2==2) return CGH<0,2,2>::t;
    return CGH<0,3,3>::t;
  }
  if(l1==1){
    if(l3==0) return CGH<1,1,0>::t;
    if(l3==1){ if(l2==0) return CGH<1,0,1>::t; if(l2==1) return CGH<1,1,1>::t; return CGH<1,2,1>::t; }
    if(l3==2){ if(l2==1) return CGH<1,1,2>::t; if(l2==2) return CGH<1,2,2>::t; return CGH<1,3,2>::t; }
    { if(l2==2) return CGH<1,2,3>::t; return CGH<1,3,3>::t; }
  }
  if(l1==2){
    if(l3==0) return CGH<2,2,0>::t;
    if(l3==1){ if(l2==1) return CGH<2,1,1>::t; if(l2==2) return CGH<2,2,1>::t; return CGH<2,3,1>::t; }
    if(l3==2){ if(l2==0) return CGH<2,0,2>::t; if(l2==1) return CGH<2,1,2>::t; if(l2==2) return CGH<2,2,2>::t; return CGH<2,3,2>::t; }
    { if(l2==1) return CGH<2,1,3>::t; if(l2==2) return CGH<2,2,3>::t; return CGH<2,3,3>::t; }
  }
  {
    if(l3==0) return CGH<3,3,0>::t;
    if(l3==1){ if(l2==2) return CGH<3,2,1>::t; return CGH<3,3,1>::t; }
    if(l3==2){ if(l2==1) return CGH<3,1,2>::t; if(l2==2) return CGH<3,2,2>::t; return CGH<3,3,2>::t; }
    { if(l2==0) return CGH<3,0,3>::t; if(l2==1) return CGH<3,1,3>::t; if(l2==2) return CGH<3,2,3>::t; return CGH<3,3,3>::t; }
  }
}

// ---------------- constexpr bucketed sparse tables ----------------
struct F2 { float x, y; };   // (coef, (float)A-index)
// t-item u32: waddr(11) | base(7)<<11 | listEntryBase<<18
// o-item uint2: w0 = wbase4(15) | momi4(9)<<15 | mi4(4)<<24 ; w1 = t4b(9) | oaddr(8)<<9
template<int NTC,int NCC,int NOC>
struct BT {
  unsigned titem[NTC];
  F2 cpk[NCC];
  unsigned ou[2*NOC];
  int nt4, nt48, nt, nc, no, ok;
};

template<int PB,int PE,int CIN,int NTC,int NCC,int NOC>
constexpr BT<NTC,NCC,NOC> build_class_(){
  BT<NTC,NCC,NOC> bt{};
  PTable pt = build_paths();
  int lb_[160]={}; int pl_[160]={};
  int nc=0, ok=1;
  for(int p=PB;p<PE;++p){
    PathC pc = pt.p[p];
    int dli=2*pc.li+1, dlf=2*pc.lf+1, dlo=2*pc.lo+1, foff=pc.lf*pc.lf;
    CGT t = get_cg_(pc.li,pc.lf,pc.lo);
    for(int o=0;o<dlo;++o){
      int lidx = pc.pobase + o;
      int start = nc;
      for(int i=0;i<dli;++i) for(int f=0;f<dlf;++f){
        double val = (double)t.v[(i*dlf+f)*dlo+o];
        if(val>1e-12 || val<-1e-12){
          if(nc<NCC){ bt.cpk[nc].x=(float)val; bt.cpk[nc].y=(float)((foff+f)*CIN+i); }
          else ok=0;
          ++nc;
        }
      }
      int len = nc-start;
      int plen = len<=4?4 : (len<=8?8:16);
      if(len>16) ok=0;
      for(int nn=len;nn<plen;++nn){ if(nc<NCC){ bt.cpk[nc].x=0.f; bt.cpk[nc].y=0.f; } else ok=0; ++nc; }
      lb_[lidx]=start; pl_[lidx]=plen;
    }
  }
  bt.nc=nc; if(nc>NCC) ok=0;
  int nt=0;
  for(int pass=0;pass<3;++pass){
    int want = pass==0?4 : (pass==1?8:16);
    for(int p=PB;p<PE;++p){
      PathC pc = pt.p[p];
      int dli=2*pc.li+1, dlo=2*pc.lo+1;
      for(int o=0;o<dlo;++o){
        int lidx = pc.pobase + o;
        if(pl_[lidx]!=want) continue;
        for(int v=0;v<pc.mi;++v){
          unsigned waddr=(unsigned)(pc.toff + o*pc.mi + v);
          unsigned base =(unsigned)(pc.ci0 + v*dli);
          if(nt<NTC) bt.titem[nt] = waddr | (base<<11) | ((unsigned)lb_[lidx]<<18);
          ++nt;
        }
      }
    }
    if(pass==0) bt.nt4=nt;
    if(pass==1) bt.nt48=nt;
  }
  bt.nt=nt; if(nt!=NTC) ok=0;

  // ---- o-items (o-major, one per (path,u,o)), packed, sorted by mi4 desc ----
  unsigned tw0[NOC]={}, tw1[NOC]={}; int tcost[NOC]={};
  int no=0;
  for(int p=PB;p<PE;++p){
    PathC pc = pt.p[p]; int dlo=2*pc.lo+1;
    for(int u=0;u<pc.mo;++u) for(int o=0;o<dlo;++o){
      int wbase4 = (pc.woff + u*pc.mi)>>2;
      int momi4  = (pc.mo*pc.mi)>>2;
      int mi4    = pc.mi>>2;
      int t4b    = (pc.toff + o*pc.mi)>>2;
      int oaddr  = pc.obase + u*dlo + o;
      if(wbase4>=(1<<15) || momi4>=(1<<9) || mi4>=(1<<4) || t4b>=(1<<9) || oaddr>=(1<<8)) ok=0;
      if(no<NOC){
        tw0[no] = (unsigned)wbase4 | ((unsigned)momi4<<15) | ((unsigned)mi4<<24);
        tw1[no] = (unsigned)t4b | ((unsigned)oaddr<<9);
        tcost[no] = mi4;
      }
      ++no;
    }
  }
  if(no!=NOC) ok=0;
  // distinct cost values, sorted desc; stable emit
  int cvs[16]={}; int ncv=0;
  for(int i=0;i<NOC;++i){
    int c=tcost[i]; bool f=false;
    for(int j=0;j<ncv;++j) if(cvs[j]==c) f=true;
    if(!f && ncv<16) cvs[ncv++]=c;
  }
  for(int i=0;i<ncv;++i){ int bi=i;
    for(int j=i+1;j<ncv;++j) if(cvs[j]>cvs[bi]) bi=j;
    int t2=cvs[i]; cvs[i]=cvs[bi]; cvs[bi]=t2;
  }
  int m=0;
  for(int ci=0;ci<ncv;++ci)
    for(int i=0;i<NOC;++i) if(tcost[i]==cvs[ci]){ bt.ou[2*m]=tw0[i]; bt.ou[2*m+1]=tw1[i]; ++m; }
  if(m!=NOC) ok=0;
  bt.no=no;
  bt.ok=ok;
  return bt;
}

constexpr auto BL0v  = build_class_<0,4,32,  512, 128, 152>();
constexpr auto BL12v = build_class_<4,38,128,1460,2560,1236>();
static_assert(BL0v.ok==1,  "L0 table overflow");
static_assert(BL12v.ok==1, "L12 table overflow");
static_assert(BL0v.nt4==512, "L0 all len<=4");
__constant__ BT<512,128,152>    c_BL0  = BL0v;
__constant__ BT<1460,2560,1236> c_BL12 = BL12v;

// scale lookup indexed by mi4 (mi/4): scale = 1/sqrt(10*mi*18)
constexpr float scl_(int mi){ return (float)(1.0/(csqrt_(10.0*mi)*csqrt_(18.0))); }
__constant__ float c_scl[9] = {0.f, scl_(4), scl_(8), scl_(12), 0.f, 0.f, scl_(24), 0.f, scl_(32)};

// ---------------- stage T bucket helper ----------------
template<int PL>
__device__ __forceinline__ void bucketT_(const unsigned* __restrict__ ti,
                                         const F2* __restrict__ cpk,
                                         const float* sA, float* sT,
                                         int i0, int i1, int tid){
  for(int i=i0+tid; i<i1; i+=256){
    unsigned e = ti[i];
    int waddr = e & 2047;
    int base  = (e>>11)&127;
    int lb    = (int)(e>>18);
    float s0 = 0.f, s1 = 0.f;   // two partial chains halve FMA dependency depth
    #pragma unroll
    for(int n=0;n<PL;n+=2){
      F2 c0 = cpk[lb+n], c1 = cpk[lb+n+1];
      s0 += c0.x * sA[(int)c0.y + base];
      s1 += c1.x * sA[(int)c1.y + base];
    }
    sT[waddr] = s0 + s1;
  }
}

// ---------------- per-layer kernel: one radial basis k per block ----------------
template<int L>
__global__ __launch_bounds__(256,5) void layer_kernel(
    const float* __restrict__ fin, const int* __restrict__ z, const float* __restrict__ table,
    const float* __restrict__ pos, const float* __restrict__ maskp,
    const float* __restrict__ rw, float* __restrict__ pout)
{
  constexpr int C_IN = (L==0)?32:128;
  constexpr int NT   = (L==0)?512:1460;
  constexpr int NO   = (L==0)?152:1236;
  constexpr int NT4  = (L==0)?BL0v.nt4 :BL12v.nt4;
  constexpr int NT48 = (L==0)?BL0v.nt48:BL12v.nt48;
  constexpr int NI_O = (NO+255)/256;
  constexpr int WB4  = (L==2)? W_DELTA4 : 0;   // layer-2 weight region shift (float4 units)

  __shared__ __align__(16) float s_fin[NA*C_IN];
  __shared__ __align__(16) float s_A[16*C_IN];
  __shared__ __align__(16) float s_T[NT];
  __shared__ float s_Y[NA*16];   // rb-prescaled Y
  __shared__ float s_out[C_OUT];

  const int tid = threadIdx.x;
  const int b = blockIdx.x / NA, a = blockIdx.x % NA;
  const int k = blockIdx.y;

  const unsigned* TI; const F2* CP; const unsigned* OU;
  if constexpr(L==0){ TI=c_BL0.titem;  CP=c_BL0.cpk;  OU=c_BL0.ou; }
  else              { TI=c_BL12.titem; CP=c_BL12.cpk; OU=c_BL12.ou; }

  // ---- prologue ----
  if(tid < C_OUT) s_out[tid] = 0.f;

  if(tid < NA){    // rb-prescaled Y[16] per neighbour j (rb folded in -> stage A saves reads+muls)
    const int j = tid;
    const float* pa = pos + (b*NA+a)*3;
    const float* pj = pos + (b*NA+j)*3;
    float dx=pj[0]-pa[0], dy=pj[1]-pa[1], dz=pj[2]-pa[2];
    float r = sqrtf(dx*dx+dy*dy+dz*dz + 1e-12f);
    float inv = 1.f/(r + 1e-9f);
    float x=dx*inv, y=dy*inv, zz=dz*inv;
    float r2 = x*x+y*y+zz*zz;
    float ck = (5.f/9.f)*(float)k;
    float tt = (r-ck)*(9.f/5.f);
    float rbv = expf(-0.5f*tt*tt)*maskp[b*NA+j];
    float* Yp = s_Y + j*16;
    Yp[0] = rbv*0.28209479177387814f;
    Yp[1] = rbv*0.4886025119029199f*y;
    Yp[2] = rbv*0.4886025119029199f*zz;
    Yp[3] = rbv*0.4886025119029199f*x;
    Yp[4] = rbv*1.0925484305920792f*x*y;
    Yp[5] = rbv*1.0925484305920792f*y*zz;
    Yp[6] = rbv*0.31539156525252005f*(3.f*zz*zz - r2);
    Yp[7] = rbv*1.0925484305920792f*x*zz;
    Yp[8] = rbv*0.5462742152960396f*(x*x - y*y);
    Yp[9] = rbv*0.5900435899266435f*y*(3.f*x*x - y*y);
    Yp[10]= rbv*2.890611442640554f*x*y*zz;
    Yp[11]= rbv*0.4570457994644658f*y*(5.f*zz*zz - r2);
    Yp[12]= rbv*0.3731763325901154f*zz*(5.f*zz*zz - 3.f*r2);
    Yp[13]= rbv*0.4570457994644658f*x*(5.f*zz*zz - r2);
    Yp[14]= rbv*1.445305721320277f*zz*(x*x - y*y);
    Yp[15]= rbv*0.5900435899266435f*x*(x*x - 3.f*y*y);
  }

  if(L==0){
    for(int i=tid;i<NA*EMBED;i+=256){
      int j = i>>5, c = i&31;
      s_fin[i] = table[z[b*NA+j]*EMBED + c];
    }
  } else {
    const float4* fg = reinterpret_cast<const float4*>(fin + b*NA*C_IN);
    float4* fs = reinterpret_cast<float4*>(s_fin);
    #pragma unroll
    for(int r=0;r<(NA*C_IN/4+255)/256;++r){
      int i = tid + r*256;
      if(i < NA*C_IN/4) fs[i] = fg[i];
    }
  }
  __syncthreads();

  // ---- stage A: A[f][c] = sum_j (rb*Y)[j,f]*fin[j,c] ----
  {
    const float4* fs4 = reinterpret_cast<const float4*>(s_fin);
    float4* sA4 = reinterpret_cast<float4*>(s_A);
    if(L==0){
      if(tid < 128){
        int f = tid>>3, c4 = tid&7;
        float4 s0 = {0.f,0.f,0.f,0.f};
        #pragma unroll
        for(int j=0;j<NA;++j){
          float ry = s_Y[j*16+f];
          float4 v = fs4[j*8 + c4];
          s0.x += ry*v.x; s0.y += ry*v.y; s0.z += ry*v.z; s0.w += ry*v.w;
        }
        sA4[f*8 + c4] = s0;
      }
    } else {
      int f0 = tid>>5, c4 = tid&31;     // rows f0 and f0+8
      float4 a0={0,0,0,0}, a1={0,0,0,0};
      #pragma unroll
      for(int j=0;j<NA;++j){
        float y0 = s_Y[j*16+f0];
        float y1 = s_Y[j*16+f0+8];
        float4 v = fs4[j*32 + c4];
        a0.x += y0*v.x; a0.y += y0*v.y; a0.z += y0*v.z; a0.w += y0*v.w;
        a1.x += y1*v.x; a1.y += y1*v.y; a1.z += y1*v.z; a1.w += y1*v.w;
      }
      sA4[(f0  )*32 + c4] = a0;
      sA4[(f0+8)*32 + c4] = a1;
    }
  }
  __syncthreads();

  // ---- stage T: sparse CG contraction ----
  bucketT_<4 >(TI, CP, s_A, s_T, 0,    NT4,  tid);
  bucketT_<8 >(TI, CP, s_A, s_T, NT4,  NT48, tid);
  bucketT_<16>(TI, CP, s_A, s_T, NT48, NT,   tid);
  __syncthreads();

  // ---- stage out (o-major, packed items): s_out[oaddr] += scale * sum_v W[k,u,v]*T[o][v] ----
  const float4* T4 = reinterpret_cast<const float4*>(s_T);
  const float4* W4 = reinterpret_cast<const float4*>(rw) + WB4;
  const uint2*  OU2 = reinterpret_cast<const uint2*>(OU);
  #pragma unroll
  for(int r=0;r<NI_O;++r){
    int idx = tid + r*256;
    if(idx < NO){
      uint2 e = OU2[idx];
      int wbase4 =  e.x & 0x7FFF;
      int momi4  = (e.x>>15) & 0x1FF;
      int mi4    = (int)(e.x>>24);
      int t4b    =  e.y & 0x1FF;
      int oaddr  = (e.y>>9) & 0xFF;
      const float4* Wp = W4 + wbase4 + k*momi4;
      const float4* Tp = T4 + t4b;
      float s = 0.f;
      for(int v4=0; v4<mi4; ++v4){
        float4 w = Wp[v4], t = Tp[v4];
        s += w.x*t.x + w.y*t.y + w.z*t.z + w.w*t.w;
      }
      atomicAdd(&s_out[oaddr], s*c_scl[mi4]);
    }
  }
  __syncthreads();

  // ---- write this k's partial ----
  if(tid < C_OUT)
    pout[(k*NB*NA + blockIdx.x)*C_OUT + tid] = s_out[tid];
}

// ---------------- epilogue: sum k-partials, gate, mask ----------------
__global__ __launch_bounds__(160) void epi_kernel(const float* __restrict__ part,
    const float* __restrict__ maskp, float* __restrict__ fout){
  __shared__ float so[C_OUT];
  __shared__ float sg[24];
  const int ba = blockIdx.x, t = threadIdx.x;
  if(t < C_OUT){
    float s = 0.f;
    #pragma unroll
    for(int kk=0;kk<10;++kk) s += part[(kk*NB*NA + ba)*C_OUT + t];
    so[t] = s;
  }
  __syncthreads();
  if(t < 24) sg[t] = 1.f/(1.f+expf(-so[24+t]));
  __syncthreads();
  if(t < C_FEAT){
    float val;
    if(t<24)       { val = fmaxf(so[t], 0.f); }
    else if(t<60)  { int r=t-24;  int v=r/3; val = so[48+r]  * sg[v]; }
    else if(t<100) { int r=t-60;  int v=r/5; val = so[84+r]  * sg[12+v]; }
    else           { int r=t-100; int v=r/7; val = so[124+r] * sg[20+v]; }
    fout[ba*C_FEAT + t] = val*maskp[ba];
  }
}

// ---------------- launch ----------------
extern "C" void kernel_launch(void* const* d_in, const int* in_sizes, int n_in,
                              void* d_out, int out_size, void* d_ws, size_t ws_size,
                              hipStream_t stream) {
  const int*   z     = (const int*)  d_in[0];
  const float* pos   = (const float*)d_in[1];
  const float* mask  = (const float*)d_in[2];
  const float* table = (const float*)d_in[3];
  const float* rw    = (const float*)d_in[4];
  float* out = (float*)d_out;
  float* ws  = (float*)d_ws;

  float* ps = ws;                        // 10*768*152 = 1,167,360 floats
  float* fA = ps + 10*NB*NA*C_OUT;       // 768*128
  float* fB = fA + NB*NA*C_FEAT;

  dim3 gl(NB*NA, 10);
  layer_kernel<0><<<gl, 256, 0, stream>>>(nullptr, z, table, pos, mask, rw, ps);
  epi_kernel<<<NB*NA, 160, 0, stream>>>(ps, mask, fA);
  layer_kernel<1><<<gl, 256, 0, stream>>>(fA, z, table, pos, mask, rw, ps);
  epi_kernel<<<NB*NA, 160, 0, stream>>>(ps, mask, fB);
  layer_kernel<2><<<gl, 256, 0, stream>>>(fB, z, table, pos, mask, rw, ps);
  epi_kernel<<<NB*NA, 160, 0, stream>>>(ps, mask, out);
}